// Round 9
// baseline (285.052 us; speedup 1.0000x reference)
//
#include <hip/hip_runtime.h>
#include <math.h>

#define BATCH 8
#define NBOX 10000
#define NCLS 80
#define KSEL 8
#define MAXT 8
#define IOU_THR 0.5f
#define SCORE_THR 0.5f
#define NEGV -1000000000.0f
#define IDXINF 0x7fffffff

#define NSUB 80             // 128-row subs per class: 80*128 = 10240 >= 10000
#define KPAD 81             // LDS stride (2-way bank aliasing = free)
#define LIVEB (1ull << 63)

typedef unsigned long long u64;

// Order-isomorphic key for (val desc, idx asc); requires v > 0 (guaranteed by
// v > SCORE_THR guard). Bigger key = better candidate. bit63 reserved.
__device__ __forceinline__ u64 pkey(float v, int n) {
    return ((u64)__float_as_uint(v) << 32) | (unsigned)(16383 - n);
}

// threshold + top-2 update (ascending n -> first-idx ties)
#define T2C(V1, I1, V2, I2, X, N)                                           \
    do {                                                                    \
        float _x = ((X) > SCORE_THR) ? (X) : NEGV;                          \
        if (_x > (V1)) { (V2)=(V1); (I2)=(I1); (V1)=_x; (I1)=(N); }         \
        else if (_x > (V2)) { (V2)=_x; (I2)=(N); }                          \
    } while (0)

// IoU suppression test, per-op IEEE rounding identical to numpy reference;
// union order = kept_area + cand_area. (validated absmax 0.0 since R1)
#define IOU_SUP(KB, KA)                                                     \
    do {                                                                    \
        float ih = fmaxf(__fsub_rn(fminf((KB).z, cb.z), fmaxf((KB).x, cb.x)), 0.0f); \
        float iw = fmaxf(__fsub_rn(fminf((KB).w, cb.w), fmaxf((KB).y, cb.y)), 0.0f); \
        float inter = __fmul_rn(ih, iw);                                    \
        float uni   = __fsub_rn(__fadd_rn((KA), carea), inter);             \
        float iou   = __fdiv_rn(inter, fmaxf(uni, 1e-9f));                  \
        if (iou > IOU_THR) sup = true;                                      \
    } while (0)

// ---------------------------------------------------------------------------
// K1: per-(batch, 128-row sub) top-2 of each of the 80 classes, as packed
// u64 keys. Reads raw (B,N,C) once, coalesced float4 across classes.
// Thread = (q,g): classes 4q..4q+3, rows g*8..g*8+7 of the sub.
// ---------------------------------------------------------------------------
__global__ __launch_bounds__(320) void class_heads(
    const float* __restrict__ scores,   // (B, N, C)
    u64* __restrict__ hk1,              // (B*C, NSUB)  top key | LIVEB
    u64* __restrict__ hk2)              // (B*C, NSUB)  second key (plain)
{
    __shared__ u64 lk[16][NCLS][2];     // 20 KB

    const int bid = blockIdx.x;         // b + 8*sub -> XCD pin
    const int b   = bid & 7;
    const int sub = bid >> 3;
    const int n0  = sub * 128;
    const int tid = threadIdx.x;
    const int q   = tid % 20;           // class quad
    const int g   = tid / 20;           // row group [0,16)

    const float* base = scores + ((size_t)b * NBOX + n0) * NCLS + 4 * q;

    float v10 = NEGV, v20 = NEGV, v11 = NEGV, v21 = NEGV;
    float v12 = NEGV, v22 = NEGV, v13 = NEGV, v23 = NEGV;
    int   i10 = IDXINF, i20 = IDXINF, i11 = IDXINF, i21 = IDXINF;
    int   i12 = IDXINF, i22 = IDXINF, i13 = IDXINF, i23 = IDXINF;

    #pragma unroll
    for (int k = 0; k < 8; ++k) {
        const int n = n0 + g * 8 + k;
        if (n < NBOX) {
            float4 x = *(const float4*)(base + (size_t)(g * 8 + k) * NCLS);
            T2C(v10, i10, v20, i20, x.x, n);
            T2C(v11, i11, v21, i21, x.y, n);
            T2C(v12, i12, v22, i22, x.z, n);
            T2C(v13, i13, v23, i23, x.w, n);
        }
    }

    const int c0 = 4 * q;
    lk[g][c0 + 0][0] = (v10 > SCORE_THR) ? pkey(v10, i10) : 0;
    lk[g][c0 + 0][1] = (v20 > SCORE_THR) ? pkey(v20, i20) : 0;
    lk[g][c0 + 1][0] = (v11 > SCORE_THR) ? pkey(v11, i11) : 0;
    lk[g][c0 + 1][1] = (v21 > SCORE_THR) ? pkey(v21, i21) : 0;
    lk[g][c0 + 2][0] = (v12 > SCORE_THR) ? pkey(v12, i12) : 0;
    lk[g][c0 + 2][1] = (v22 > SCORE_THR) ? pkey(v22, i22) : 0;
    lk[g][c0 + 3][0] = (v13 > SCORE_THR) ? pkey(v13, i13) : 0;
    lk[g][c0 + 3][1] = (v23 > SCORE_THR) ? pkey(v23, i23) : 0;
    __syncthreads();

    if (tid < NCLS) {
        u64 h1 = 0, h2 = 0;
        #pragma unroll
        for (int g2 = 0; g2 < 16; ++g2) {
            u64 a1 = lk[g2][tid][0], a2 = lk[g2][tid][1];   // a1 >= a2
            if (a1 > h1) { u64 t = h1; h1 = a1; h2 = (a2 > t) ? a2 : t; }
            else if (a1 > h2) h2 = a1;
        }
        const size_t o = (size_t)(b * NCLS + tid) * NSUB + sub;
        hk1[o] = h1 ? (h1 | LIVEB) : 0;
        hk2[o] = h2;
    }
}

// ---------------------------------------------------------------------------
// K2: ONE LANE PER CLASS (32 classes per 64-thread block, 20 blocks).
// Per-class LDS state per sub: av = live key (bit63) | floor key | 0=done,
// sv = successor key. Round = scalar 80-slot scan; consume (IoU vs kept
// boxes in named regs) or exact rescan of one 128-row sub below its floor.
// No cross-lane ops, no barriers in the loop; SIMT amortizes 32 classes.
// ---------------------------------------------------------------------------
__global__ __launch_bounds__(64) void nms_serial(
    const u64* __restrict__ hk1,
    const u64* __restrict__ hk2,
    const float* __restrict__ scores,   // raw (B,N,C)
    const float* __restrict__ boxes,    // (B,N,4)
    float* __restrict__ ws_msc,
    float4* __restrict__ ws_box)
{
    __shared__ u64 avs[32 * KPAD];      // 20.7 KB
    __shared__ u64 svs[32 * KPAD];      // 20.7 KB

    const int g   = blockIdx.x;         // 0..19
    const int tid = threadIdx.x;
    const int bc0 = g * 32;

    for (int i = tid; i < 32 * NSUB; i += 64) {
        const int cls = i / NSUB, sub = i - cls * NSUB;
        avs[cls * KPAD + sub] = hk1[(size_t)bc0 * NSUB + i];
        svs[cls * KPAD + sub] = hk2[(size_t)bc0 * NSUB + i];
    }
    __syncthreads();
    if (tid >= 32) return;

    const int l  = tid;
    const int bc = bc0 + l;
    const int b  = bc / NCLS;
    const int c  = bc - b * NCLS;
    const float*  raw  = scores + (size_t)b * NBOX * NCLS + c;
    const float4* box4 = (const float4*)(boxes + (size_t)b * NBOX * 4);
    u64* av = avs + l * KPAD;
    u64* sv = svs + l * KPAD;

    float4 kb0, kb1, kb2, kb3, kb4, kb5, kb6, kb7;
    float  ka0=0, ka1=0, ka2=0, ka3=0, ka4=0, ka5=0, ka6=0, ka7=0;
    kb0 = kb1 = kb2 = kb3 = kb4 = kb5 = kb6 = kb7 = make_float4(0, 0, 0, 0);
    int kept = 0;

    for (;;) {
        // ---- scan 80 slots, 4-way ILP (live max m*, blind-floor max f*) ----
        u64 m0=0,m1=0,m2=0,m3=0, f0=0,f1=0,f2=0,f3=0;
        int km0=0,km1=0,km2=0,km3=0, kf0=0,kf1=0,kf2=0,kf3=0;
        #define SCAN1(J)                                                    \
            do {                                                            \
                u64 a = av[k + J];                                          \
                u64 lv = (a >> 63) ? a : 0;                                 \
                u64 fv = (a >> 63) ? 0 : a;                                 \
                if (lv > m##J) { m##J = lv; km##J = k + J; }                \
                if (fv > f##J) { f##J = fv; kf##J = k + J; }                \
            } while (0)
        #pragma unroll 5
        for (int k = 0; k < NSUB; k += 4) { SCAN1(0); SCAN1(1); SCAN1(2); SCAN1(3); }
        #undef SCAN1
        u64 m = m0; int km = km0;
        if (m1 > m) { m = m1; km = km1; }
        if (m2 > m) { m = m2; km = km2; }
        if (m3 > m) { m = m3; km = km3; }
        u64 bf = f0; int kf = kf0;
        if (f1 > bf) { bf = f1; kf = kf1; }
        if (f2 > bf) { bf = f2; kf = kf2; }
        if (f3 > bf) { bf = f3; kf = kf3; }

        const u64 mk = m & ~LIVEB;

        if (bf > mk) {
            // exact rescan of sub kf: top-2 strictly below floor key bf.
            // Floor cleared (revive) or sub exhausted -> terminates.
            const int nb = kf << 7;
            u64 t1 = 0, t2 = 0;
            #pragma unroll 4
            for (int r = 0; r < 128; ++r) {
                const int n = nb + r;
                if (n < NBOX) {
                    float x = raw[(size_t)n * NCLS];
                    if (x > SCORE_THR) {
                        u64 kx = pkey(x, n);
                        if (kx < bf) {
                            if (kx > t1) { t2 = t1; t1 = kx; }
                            else if (kx > t2) t2 = kx;
                        }
                    }
                }
            }
            av[kf] = t1 ? (t1 | LIVEB) : 0;
            sv[kf] = t2;
            continue;
        }
        if (m == 0) break;                   // all subs exhausted

        // ---- consume best candidate ----
        const int   n  = 16383 - (int)(mk & 0xFFFFFFFFull);
        const float bv = __uint_as_float((unsigned)(mk >> 32));
        const float4 cb = box4[n];           // per-lane gather
        const float carea = __fmul_rn(__fsub_rn(cb.z, cb.x), __fsub_rn(cb.w, cb.y));

        bool sup = false;
        if (kept > 0) IOU_SUP(kb0, ka0);
        if (kept > 1) IOU_SUP(kb1, ka1);
        if (kept > 2) IOU_SUP(kb2, ka2);
        if (kept > 3) IOU_SUP(kb3, ka3);
        if (kept > 4) IOU_SUP(kb4, ka4);
        if (kept > 5) IOU_SUP(kb5, ka5);
        if (kept > 6) IOU_SUP(kb6, ka6);
        if (kept > 7) IOU_SUP(kb7, ka7);

        if (!sup) {
            const int o = bc * KSEL + kept;
            ws_msc[o] = bv;
            ws_box[o] = cb;
            if      (kept == 0) { kb0 = cb; ka0 = carea; }
            else if (kept == 1) { kb1 = cb; ka1 = carea; }
            else if (kept == 2) { kb2 = cb; ka2 = carea; }
            else if (kept == 3) { kb3 = cb; ka3 = carea; }
            else if (kept == 4) { kb4 = cb; ka4 = carea; }
            else if (kept == 5) { kb5 = cb; ka5 = carea; }
            else if (kept == 6) { kb6 = cb; ka6 = carea; }
            else                { kb7 = cb; ka7 = carea; }
            kept++;
        }

        const u64 s = sv[km];
        av[km] = s ? (s | LIVEB) : mk;       // successor, or become floor
        sv[km] = 0;
        if (kept == MAXT) break;
    }

    for (int k2 = kept; k2 < MAXT; ++k2) {
        const int o = bc * KSEL + k2;
        ws_msc[o] = NEGV;
        ws_box[o] = make_float4(0.f, 0.f, 0.f, 0.f);
    }
}

// ---------------------------------------------------------------------------
// K3: one block per batch, register-resident stable top-MAXT over 640 slots.
// (R4 code, validated)
// ---------------------------------------------------------------------------
__global__ __launch_bounds__(256) void topk_combine(
    const float* __restrict__ ws_msc,
    const float4* __restrict__ ws_box,
    float* __restrict__ out)
{
    __shared__ float red_val[2][4];
    __shared__ int   red_idx[2][4];

    const int b = blockIdx.x;
    const int tid = threadIdx.x;
    const float* msc = ws_msc + b * NCLS * KSEL;

    float v0 = (tid       < NCLS * KSEL) ? msc[tid]       : -INFINITY;
    float v1 = (tid + 256 < NCLS * KSEL) ? msc[tid + 256] : -INFINITY;
    float v2 = (tid + 512 < NCLS * KSEL) ? msc[tid + 512] : -INFINITY;

    const int OFF_SC = BATCH * MAXT * 4;
    const int OFF_CL = OFF_SC + BATCH * MAXT;
    const int OFF_VD = OFF_CL + BATCH * MAXT;

    int cnt = 0;
    int p = 0;
    #pragma unroll
    for (int t = 0; t < MAXT; ++t) {
        float bv = v0; int bi = tid;
        if (v1 > bv) { bv = v1; bi = tid + 256; }   // ascending i -> first max
        if (v2 > bv) { bv = v2; bi = tid + 512; }
        #pragma unroll
        for (int off = 32; off > 0; off >>= 1) {
            float ov = __shfl_down(bv, off, 64);
            int   oi = __shfl_down(bi, off, 64);
            if (ov > bv || (ov == bv && oi < bi)) { bv = ov; bi = oi; }
        }
        if ((tid & 63) == 0) { red_val[p][tid >> 6] = bv; red_idx[p][tid >> 6] = bi; }
        __syncthreads();
        bv = red_val[p][0]; bi = red_idx[p][0];
        #pragma unroll
        for (int w = 1; w < 4; ++w) {
            float ov = red_val[p][w]; int oi = red_idx[p][w];
            if (ov > bv || (ov == bv && oi < bi)) { bv = ov; bi = oi; }
        }
        p ^= 1;

        const bool valid = bv > SCORE_THR;
        cnt += valid ? 1 : 0;
        if (tid == t) {
            float4 bx = ws_box[b * NCLS * KSEL + bi];
            float* ob = out + ((size_t)b * MAXT + t) * 4;
            ob[0] = valid ? fminf(fmaxf(bx.x, 0.0f), 1.0f) : 0.0f;
            ob[1] = valid ? fminf(fmaxf(bx.y, 0.0f), 1.0f) : 0.0f;
            ob[2] = valid ? fminf(fmaxf(bx.z, 0.0f), 1.0f) : 0.0f;
            ob[3] = valid ? fminf(fmaxf(bx.w, 0.0f), 1.0f) : 0.0f;
            out[OFF_SC + b * MAXT + t] = valid ? bv : 0.0f;
            out[OFF_CL + b * MAXT + t] = valid ? (float)(bi >> 3) : 0.0f;
        }
        if (tid == (bi & 255)) {
            int w = bi >> 8;
            if (w == 0) v0 = -INFINITY;
            else if (w == 1) v1 = -INFINITY;
            else v2 = -INFINITY;
        }
    }
    if (tid == 0) out[OFF_VD + b] = (float)cnt;
}

extern "C" void kernel_launch(void* const* d_in, const int* in_sizes, int n_in,
                              void* d_out, int out_size, void* d_ws, size_t ws_size,
                              hipStream_t stream) {
    const float* boxes  = (const float*)d_in[0];   // (B, N, 1, 4)
    const float* scores = (const float*)d_in[1];   // (B, N, C)
    float* out = (float*)d_out;

    // ws: hk1 (400 KB) | hk2 (400 KB) | msc (20 KB) | box (80 KB)
    const size_t nk = (size_t)BATCH * NCLS * NSUB;           // 51200
    u64* hk1 = (u64*)d_ws;
    u64* hk2 = hk1 + nk;
    float*  ws_msc = (float*)(hk2 + nk);
    float4* ws_box = (float4*)((char*)ws_msc + (size_t)BATCH * NCLS * KSEL * 4);

    class_heads<<<BATCH * NSUB, 320, 0, stream>>>(scores, hk1, hk2);
    nms_serial<<<20, 64, 0, stream>>>(hk1, hk2, scores, boxes, ws_msc, ws_box);
    topk_combine<<<BATCH, 256, 0, stream>>>(ws_msc, ws_box, out);
}

// Round 10
// 39.615 us; speedup vs baseline: 7.1955x; 7.1955x over previous
//
#include <hip/hip_runtime.h>
#include <math.h>

#define BATCH 8
#define NBOX 10000
#define NCLS 80
#define KSEL 8
#define MAXT 8
#define IOU_THR 0.5f
#define SCORE_THR 0.5f
#define NEGV -1000000000.0f
#define IDXINF 0x7fffffff

#define NSUB 80             // 128-row subs per class (K1): 80*128 = 10240
#define CHROWS 640          // K2 chunk = 5 subs = 640 rows; 16 chunks
typedef unsigned long long u64;

// Packed key, order-isomorphic to (val desc, idx asc); val>SCORE_THR>0 so
// float bits are monotone. bits: [51:20] value, [19:6] 16383-idx, [5:0] lane.
__device__ __forceinline__ u64 pk20(float v, int n) {
    return ((u64)__float_as_uint(v) << 20) | ((u64)(16383 - n) << 6);
}

// threshold + top-2 update (ascending n -> first-idx ties)
#define T2C(V1, I1, V2, I2, X, N)                                           \
    do {                                                                    \
        float _x = ((X) > SCORE_THR) ? (X) : NEGV;                          \
        if (_x > (V1)) { (V2)=(V1); (I2)=(I1); (V1)=_x; (I1)=(N); }         \
        else if (_x > (V2)) { (V2)=_x; (I2)=(N); }                          \
    } while (0)

// sorted-4 insertion (descending); zero keys never displace real ones
#define INS4(T1, T2, T3, T4, K)                                             \
    do { u64 _k = (K);                                                      \
        if (_k > (T1)) { (T4)=(T3); (T3)=(T2); (T2)=(T1); (T1)=_k; }        \
        else if (_k > (T2)) { (T4)=(T3); (T3)=(T2); (T2)=_k; }              \
        else if (_k > (T3)) { (T4)=(T3); (T3)=_k; }                         \
        else if (_k > (T4)) { (T4)=_k; }                                    \
    } while (0)

// IoU suppression, per-op IEEE rounding identical to numpy reference;
// union order = kept_area + cand_area. (validated absmax 0.0 since R1)
#define IOU_SUP(KB, KA)                                                     \
    do {                                                                    \
        float ih = fmaxf(__fsub_rn(fminf((KB).z, cb.z), fmaxf((KB).x, cb.x)), 0.0f); \
        float iw = fmaxf(__fsub_rn(fminf((KB).w, cb.w), fmaxf((KB).y, cb.y)), 0.0f); \
        float inter = __fmul_rn(ih, iw);                                    \
        float uni   = __fsub_rn(__fadd_rn((KA), carea), inter);             \
        float iou   = __fdiv_rn(inter, fmaxf(uni, 1e-9f));                  \
        if (iou > IOU_THR) sup = true;                                      \
    } while (0)

__device__ __forceinline__ float aload(const float* p) {
    return __hip_atomic_load(p, __ATOMIC_RELAXED, __HIP_MEMORY_SCOPE_AGENT);
}

// ---------------------------------------------------------------------------
// K1: per-(batch, 128-row sub) top-2 packed keys for all 80 classes, stored
// as adjacent pairs. Reads raw (B,N,C) once, coalesced float4 across classes.
// Thread = (q,g): classes 4q..4q+3, rows g*8..g*8+7. Block 0 zeroes cnt.
// ---------------------------------------------------------------------------
__global__ __launch_bounds__(320) void class_heads(
    const float* __restrict__ scores,   // (B, N, C)
    u64* __restrict__ hk,               // (B*C, NSUB, 2) packed keys
    int* __restrict__ cnt)              // (BATCH) completion counters
{
    __shared__ u64 lk[16][NCLS][2];     // 20 KB

    const int bid = blockIdx.x;         // b + 8*sub -> XCD pin
    const int b   = bid & 7;
    const int sub = bid >> 3;
    const int n0  = sub * 128;
    const int tid = threadIdx.x;
    const int q   = tid % 20;           // class quad
    const int g   = tid / 20;           // row group [0,16)

    if (bid == 0 && tid < BATCH) cnt[tid] = 0;

    const float* base = scores + ((size_t)b * NBOX + n0) * NCLS + 4 * q;

    float v10 = NEGV, v20 = NEGV, v11 = NEGV, v21 = NEGV;
    float v12 = NEGV, v22 = NEGV, v13 = NEGV, v23 = NEGV;
    int   i10 = IDXINF, i20 = IDXINF, i11 = IDXINF, i21 = IDXINF;
    int   i12 = IDXINF, i22 = IDXINF, i13 = IDXINF, i23 = IDXINF;

    #pragma unroll
    for (int k = 0; k < 8; ++k) {
        const int n = n0 + g * 8 + k;
        if (n < NBOX) {
            float4 x = *(const float4*)(base + (size_t)(g * 8 + k) * NCLS);
            T2C(v10, i10, v20, i20, x.x, n);
            T2C(v11, i11, v21, i21, x.y, n);
            T2C(v12, i12, v22, i22, x.z, n);
            T2C(v13, i13, v23, i23, x.w, n);
        }
    }

    const int c0 = 4 * q;
    lk[g][c0 + 0][0] = (v10 > SCORE_THR) ? pk20(v10, i10) : 0;
    lk[g][c0 + 0][1] = (v20 > SCORE_THR) ? pk20(v20, i20) : 0;
    lk[g][c0 + 1][0] = (v11 > SCORE_THR) ? pk20(v11, i11) : 0;
    lk[g][c0 + 1][1] = (v21 > SCORE_THR) ? pk20(v21, i21) : 0;
    lk[g][c0 + 2][0] = (v12 > SCORE_THR) ? pk20(v12, i12) : 0;
    lk[g][c0 + 2][1] = (v22 > SCORE_THR) ? pk20(v22, i22) : 0;
    lk[g][c0 + 3][0] = (v13 > SCORE_THR) ? pk20(v13, i13) : 0;
    lk[g][c0 + 3][1] = (v23 > SCORE_THR) ? pk20(v23, i23) : 0;
    __syncthreads();

    if (tid < NCLS) {
        u64 h1 = 0, h2 = 0;
        #pragma unroll
        for (int g2 = 0; g2 < 16; ++g2) {
            u64 a1 = lk[g2][tid][0], a2 = lk[g2][tid][1];   // a1 >= a2
            if (a1 > h1) { u64 t = h1; h1 = a1; h2 = (a2 > t) ? a2 : t; }
            else if (a1 > h2) h2 = a1;
        }
        u64* o = hk + ((size_t)(b * NCLS + tid) * NSUB + sub) * 2;
        o[0] = h1; o[1] = h2;
    }
}

// ---------------------------------------------------------------------------
// K2: one WAVE per class (4 waves/block, 160 blocks). 16 chunks x 640 rows,
// top-4 heads/chunk = 64 head lanes. Per round: ONE u64 butterfly (live max);
// floor butterfly only when some chunk is blind (rare with top-4). Rescan
// refills the full top-4 below the floor. Winner box via lane shuffles, IoU
// vs kept boxes in named registers. Last block per batch runs fused top-8.
// ---------------------------------------------------------------------------
__global__ __launch_bounds__(256) void nms_extract(
    const u64* __restrict__ hk,
    const float* __restrict__ scores,   // raw (B,N,C)
    const float* __restrict__ boxes,    // (B,N,4)
    float* __restrict__ ws_msc,
    float* __restrict__ ws_box,         // (B*C*K, 4) floats
    int*   __restrict__ cnt,
    float* __restrict__ out)
{
    __shared__ float rv[2][4];
    __shared__ int   ri[2][4];
    __shared__ int   s_old;

    const int bid = blockIdx.x;         // b + 8*grp -> XCD pin
    const int b   = bid & 7;
    const int grp = bid >> 3;
    const int w   = threadIdx.x >> 6;
    const int l   = threadIdx.x & 63;
    const int tid = threadIdx.x;
    const int c   = grp * 4 + w;
    const int bc  = b * NCLS + c;

    const float*  raw  = scores + (size_t)b * NBOX * NCLS + c;
    const float4* box4 = (const float4*)(boxes + (size_t)b * NBOX * 4);

    const int ch = l >> 2;              // this lane's chunk [0,16)
    const int r4 = l & 3;               // rank within chunk

    // ---- init: merge the chunk's 5 sub-pairs -> sorted top-4 ----
    u64 t1 = 0, t2 = 0, t3 = 0, t4 = 0;
    {
        const u64* hp = hk + ((size_t)bc * NSUB + ch * 5) * 2;
        #pragma unroll
        for (int j = 0; j < 5; ++j) {
            INS4(t1, t2, t3, t4, hp[2 * j]);
            INS4(t1, t2, t3, t4, hp[2 * j + 1]);
        }
    }
    u64 key = (r4 == 0) ? t1 : (r4 == 1) ? t2 : (r4 == 2) ? t3 : t4;
    bool exh = (t4 == 0);               // <4 candidates -> nothing hidden
    key = key ? (key | (u64)l) : 0;
    bool dead = (key == 0);
    u64 fl = 0;                         // chunk floor = last consumed key

    float4 bx = make_float4(0.f, 0.f, 0.f, 0.f);
    float  barea = 0.f;
    if (!dead) {
        const int n = 16383 - (int)((key >> 6) & 0x3FFF);
        bx = box4[n];
        barea = __fmul_rn(__fsub_rn(bx.z, bx.x), __fsub_rn(bx.w, bx.y));
    }

    float4 kb0, kb1, kb2, kb3, kb4, kb5, kb6, kb7;
    float  ka0=0, ka1=0, ka2=0, ka3=0, ka4=0, ka5=0, ka6=0, ka7=0;
    kb0 = kb1 = kb2 = kb3 = kb4 = kb5 = kb6 = kb7 = make_float4(0, 0, 0, 0);
    int kept = 0;

    for (;;) {
        u64 lk_ = dead ? 0ull : key;
        #pragma unroll
        for (int off = 1; off < 64; off <<= 1) {
            u64 o = __shfl_xor(lk_, off, 64);
            if (o > lk_) lk_ = o;
        }
        const u64 db = __ballot(dead);
        const bool blind = (((db >> (l & ~3)) & 15ull) == 15ull)
                         && (fl != 0) && !exh;
        if (__any(blind)) {
            u64 fk = blind ? fl : 0ull;
            #pragma unroll
            for (int off = 1; off < 64; off <<= 1) {
                u64 o = __shfl_xor(fk, off, 64);
                if (o > fk) fk = o;
            }
            if (fk > lk_) {
                // exact rescan of blind chunk: top-4 strictly below floor
                const int chr = ((int)(fk & 63ull)) >> 2;
                const u64 flc = fk & ~63ull;
                const int nb  = chr * CHROWS;
                u64 s1 = 0, s2 = 0, s3 = 0, s4 = 0;
                #pragma unroll
                for (int qq = 0; qq < 10; ++qq) {
                    const int n = nb + qq * 64 + l;
                    if (n < NBOX) {
                        float x = raw[(size_t)n * NCLS];
                        if (x > SCORE_THR) {
                            u64 kx = pk20(x, n);
                            if (kx < flc) INS4(s1, s2, s3, s4, kx);
                        }
                    }
                }
                #pragma unroll
                for (int off = 1; off < 64; off <<= 1) {
                    u64 o1 = __shfl_xor(s1, off, 64);
                    u64 o2 = __shfl_xor(s2, off, 64);
                    u64 o3 = __shfl_xor(s3, off, 64);
                    u64 o4 = __shfl_xor(s4, off, 64);
                    INS4(s1, s2, s3, s4, o1); INS4(s1, s2, s3, s4, o2);
                    INS4(s1, s2, s3, s4, o3); INS4(s1, s2, s3, s4, o4);
                }
                if (ch == chr) {
                    u64 t = (r4 == 0) ? s1 : (r4 == 1) ? s2
                          : (r4 == 2) ? s3 : s4;
                    exh  = (s4 == 0);
                    key  = t ? (t | (u64)l) : 0;
                    dead = (key == 0);
                    fl   = 0;
                    if (!dead) {
                        const int n = 16383 - (int)((key >> 6) & 0x3FFF);
                        bx = box4[n];
                        barea = __fmul_rn(__fsub_rn(bx.z, bx.x),
                                          __fsub_rn(bx.w, bx.y));
                    }
                }
                continue;
            }
        }
        if (lk_ == 0ull) break;

        const int   owner = (int)(lk_ & 63ull);
        const int   bi    = 16383 - (int)((lk_ >> 6) & 0x3FFF);
        const float bv    = __uint_as_float((unsigned)(lk_ >> 20));
        float4 cb;
        cb.x = __shfl(bx.x, owner, 64);
        cb.y = __shfl(bx.y, owner, 64);
        cb.z = __shfl(bx.z, owner, 64);
        cb.w = __shfl(bx.w, owner, 64);
        const float carea = __shfl(barea, owner, 64);

        bool sup = false;
        if (kept > 0) IOU_SUP(kb0, ka0);
        if (kept > 1) IOU_SUP(kb1, ka1);
        if (kept > 2) IOU_SUP(kb2, ka2);
        if (kept > 3) IOU_SUP(kb3, ka3);
        if (kept > 4) IOU_SUP(kb4, ka4);
        if (kept > 5) IOU_SUP(kb5, ka5);
        if (kept > 6) IOU_SUP(kb6, ka6);
        if (kept > 7) IOU_SUP(kb7, ka7);

        if (!sup) {
            if (l == 0) {
                const int o = bc * KSEL + kept;
                ws_msc[o] = bv;
                float* ob = ws_box + (size_t)o * 4;
                ob[0] = cb.x; ob[1] = cb.y; ob[2] = cb.z; ob[3] = cb.w;
            }
            if      (kept == 0) { kb0 = cb; ka0 = carea; }
            else if (kept == 1) { kb1 = cb; ka1 = carea; }
            else if (kept == 2) { kb2 = cb; ka2 = carea; }
            else if (kept == 3) { kb3 = cb; ka3 = carea; }
            else if (kept == 4) { kb4 = cb; ka4 = carea; }
            else if (kept == 5) { kb5 = cb; ka5 = carea; }
            else if (kept == 6) { kb6 = cb; ka6 = carea; }
            else                { kb7 = cb; ka7 = carea; }
            kept++;
        }

        if (l == owner) dead = true;
        if (ch == (owner >> 2) && !exh) fl = lk_;   // chunk floor update
        if (kept == MAXT) break;
    }

    if (l == 0) {
        for (int k2 = kept; k2 < MAXT; ++k2) {
            const int o = bc * KSEL + k2;
            ws_msc[o] = NEGV;
            float* ob = ws_box + (size_t)o * 4;
            ob[0] = 0.f; ob[1] = 0.f; ob[2] = 0.f; ob[3] = 0.f;
        }
    }

    // ---- last-block election for this batch -> fused top-8 combine ----
    __syncthreads();
    if (tid == 0) {
        __threadfence();
        s_old = atomicAdd(&cnt[b], 1);
    }
    __syncthreads();
    if (s_old != (NCLS / 4) - 1) return;
    __threadfence();

    const float* msc = ws_msc + b * NCLS * KSEL;
    float v0 = aload(msc + tid);
    float v1 = aload(msc + tid + 256);
    float v2 = (tid + 512 < NCLS * KSEL) ? aload(msc + tid + 512) : -INFINITY;

    const int OFF_SC = BATCH * MAXT * 4;
    const int OFF_CL = OFF_SC + BATCH * MAXT;
    const int OFF_VD = OFF_CL + BATCH * MAXT;

    int tot = 0;
    int p = 0;
    #pragma unroll
    for (int t = 0; t < MAXT; ++t) {
        float bv = v0; int bi = tid;
        if (v1 > bv) { bv = v1; bi = tid + 256; }   // ascending i -> first max
        if (v2 > bv) { bv = v2; bi = tid + 512; }
        #pragma unroll
        for (int off = 32; off > 0; off >>= 1) {
            float ov = __shfl_down(bv, off, 64);
            int   oi = __shfl_down(bi, off, 64);
            if (ov > bv || (ov == bv && oi < bi)) { bv = ov; bi = oi; }
        }
        if ((tid & 63) == 0) { rv[p][tid >> 6] = bv; ri[p][tid >> 6] = bi; }
        __syncthreads();
        bv = rv[p][0]; bi = ri[p][0];
        #pragma unroll
        for (int w2 = 1; w2 < 4; ++w2) {
            float ov = rv[p][w2]; int oi = ri[p][w2];
            if (ov > bv || (ov == bv && oi < bi)) { bv = ov; bi = oi; }
        }
        p ^= 1;

        const bool valid = bv > SCORE_THR;
        tot += valid ? 1 : 0;
        if (tid == t) {
            const float* sb = ws_box + ((size_t)b * NCLS * KSEL + bi) * 4;
            float bx0 = aload(sb + 0), bx1 = aload(sb + 1);
            float bx2 = aload(sb + 2), bx3 = aload(sb + 3);
            float* ob = out + ((size_t)b * MAXT + t) * 4;
            ob[0] = valid ? fminf(fmaxf(bx0, 0.0f), 1.0f) : 0.0f;
            ob[1] = valid ? fminf(fmaxf(bx1, 0.0f), 1.0f) : 0.0f;
            ob[2] = valid ? fminf(fmaxf(bx2, 0.0f), 1.0f) : 0.0f;
            ob[3] = valid ? fminf(fmaxf(bx3, 0.0f), 1.0f) : 0.0f;
            out[OFF_SC + b * MAXT + t] = valid ? bv : 0.0f;
            out[OFF_CL + b * MAXT + t] = valid ? (float)(bi >> 3) : 0.0f;
        }
        if (tid == (bi & 255)) {
            int w2 = bi >> 8;
            if (w2 == 0) v0 = -INFINITY;
            else if (w2 == 1) v1 = -INFINITY;
            else v2 = -INFINITY;
        }
    }
    if (tid == 0) out[OFF_VD + b] = (float)tot;
}

extern "C" void kernel_launch(void* const* d_in, const int* in_sizes, int n_in,
                              void* d_out, int out_size, void* d_ws, size_t ws_size,
                              hipStream_t stream) {
    const float* boxes  = (const float*)d_in[0];   // (B, N, 1, 4)
    const float* scores = (const float*)d_in[1];   // (B, N, C)
    float* out = (float*)d_out;

    // ws: hk (800 KB) | msc (20 KB) | box (80 KB) | cnt (32 B)
    const size_t nk = (size_t)BATCH * NCLS * NSUB * 2;       // 102400 keys
    char* p = (char*)d_ws;
    u64*   hk     = (u64*)p;          p += nk * 8;
    float* ws_msc = (float*)p;        p += (size_t)BATCH * NCLS * KSEL * 4;
    float* ws_box = (float*)p;        p += (size_t)BATCH * NCLS * KSEL * 16;
    int*   cnt    = (int*)p;

    class_heads<<<BATCH * NSUB, 320, 0, stream>>>(scores, hk, cnt);
    nms_extract<<<BATCH * (NCLS / 4), 256, 0, stream>>>(hk, scores, boxes,
                                                        ws_msc, ws_box,
                                                        cnt, out);
}